// Round 18
// baseline (100.970 us; speedup 1.0000x reference)
//
#include <hip/hip_runtime.h>
#include <stdint.h>

#define NEGC (-1.0e9f)

typedef __attribute__((ext_vector_type(8))) short bf16x8;
typedef __attribute__((ext_vector_type(4))) float f32x4;

#define VMCNT0 asm volatile("s_waitcnt vmcnt(0)" ::: "memory")
#define LGKMCNT0 asm volatile("s_waitcnt lgkmcnt(0)" ::: "memory")
#define SCHED0 __builtin_amdgcn_sched_barrier(0)

// g_S2H/g_S2L: seq2 bf16 hi/lo row-major [b][m][d]   (phase-A staged source)
//   R16 lesson: the K-side lo correction is numerically load-bearing (dropping
//   it -> out0 absmax 0.113 > 0.101 threshold). 3-MFMA split stays.
// g_VF: V^T bf16 fragment-order chunks [b][wc 2][ms 16][c 4][lane 64][8]
//   lane l=(q*16+fr): V^T[d = wc*64+c*16+fr][m = ms*32+q*8 .. +8]   (R9-verified)
__device__ __align__(16) unsigned short g_S2H[32u * 512u * 128u];
__device__ __align__(16) unsigned short g_S2L[32u * 512u * 128u];
__device__ __align__(16) unsigned short g_VF[32u * 128u * 512u];
__device__ float g_a1log[32 * 2048];   // a1 logits (bidir_main -> k_gemv)

__device__ __forceinline__ unsigned short f2bf(float f) {
    union { float f; unsigned int u; } v; v.f = f;
    unsigned int r = v.u + 0x7fffu + ((v.u >> 16) & 1u);
    return (unsigned short)(r >> 16);
}
__device__ __forceinline__ float bf2f(unsigned short h) {
    union { float f; unsigned int u; } v; v.u = ((unsigned int)h) << 16;
    return v.f;
}

__device__ __forceinline__ void gl_lds16(const void* g, void* l) {
    __builtin_amdgcn_global_load_lds(
        (const __attribute__((address_space(1))) unsigned int*)g,
        (__attribute__((address_space(3))) unsigned int*)l, 16, 0, 0);
}

// ---- prep: seq2 -> row-major hi/lo split + fragment-order V^T. 512 blocks. ----
__global__ __launch_bounds__(256) void k_prep(const float* __restrict__ seq2) {
    __shared__ unsigned short Lh[32 * 136];
    const int b = blockIdx.x >> 4, c = blockIdx.x & 15, t = threadIdx.x;
    const int m0 = c * 32;

    // pass 1: rows [m0,+32) -> S2H/S2L row-major; hi also staged in LDS
    const float4* src = (const float4*)(seq2 + (size_t)(b * 512 + m0) * 128);
    ushort4* dh = (ushort4*)(g_S2H + (size_t)(b * 512 + m0) * 128);
    ushort4* dl = (ushort4*)(g_S2L + (size_t)(b * 512 + m0) * 128);
#pragma unroll
    for (int p = 0; p < 4; ++p) {
        int idx = p * 256 + t;
        int row = idx >> 5, c4 = idx & 31;
        float4 v = src[idx];
        float vs[4] = {v.x, v.y, v.z, v.w};
        unsigned short hh[4], ll[4];
#pragma unroll
        for (int i = 0; i < 4; ++i) { hh[i] = f2bf(vs[i]); ll[i] = f2bf(vs[i] - bf2f(hh[i])); }
        ushort4 uh{hh[0], hh[1], hh[2], hh[3]};
        ushort4 ul{ll[0], ll[1], ll[2], ll[3]};
        dh[idx] = uh;
        dl[idx] = ul;
#pragma unroll
        for (int i = 0; i < 4; ++i) Lh[row * 136 + c4 * 4 + i] = hh[i];
    }
    __syncthreads();

    // pass 2 (R9-verified): V-frags, this block's 32 m-cols = ms chunk (m0>>5)
    {
        const int l = t & 63, q = (t >> 4) & 3, fr = t & 15;
        const int ms = m0 >> 5;
#pragma unroll
        for (int pass = 0; pass < 2; ++pass) {
            int id = pass * 4 + (t >> 6);        // 0..7
            int wcd = id >> 2, cc = id & 3;
            int d = wcd * 64 + cc * 16 + fr;
            unsigned short pk[8];
#pragma unroll
            for (int j = 0; j < 8; ++j) pk[j] = Lh[(q * 8 + j) * 136 + d];
            size_t chunk = (size_t)b * 65536 + (size_t)wcd * 32768
                         + (size_t)ms * 2048 + cc * 512 + l * 8;
            *(bf16x8*)(g_VF + chunk) = *(bf16x8*)pk;
        }
    }
}

// ---- LDS layout (bytes): ONE 32K region, phase-overlaid ----
// phase A: wave-PRIVATE K buffers: wave w @ w*8192 {hi 4K | lo 4K} (no barriers;
//          each wave stages/consumes only its own wc-half rows; wr-pairs duplicate)
// phase B: REDm @0 (256B), REDs @256 (256B)   (after post-phase-A barrier)
// phase C: A2 bf16 [32][512] @0 (32K)          (written after RED reads + barrier)
#define LDS_TOTAL 32768

__global__ __launch_bounds__(256, 4) void bidir_main(
    const float* __restrict__ seq1,
    const int* __restrict__ m1, const int* __restrict__ m2,
    float* __restrict__ out0, float* __restrict__ a2out,
    float* __restrict__ out2)
{
    __shared__ __align__(16) char smem[LDS_TOTAL];

    const int t = threadIdx.x, lane = t & 63, w = t >> 6;
    const int wr = w >> 1, wc = w & 1, q = lane >> 4, fr = lane & 15;
    const int orig = blockIdx.x;
    const int swzb = (orig & 7) * 256 + (orig >> 3);   // XCD-contiguous
    const int b = swzb >> 6, n0 = (swzb & 63) << 5;

    float* REDm = (float*)(smem);
    float* REDs = (float*)(smem + 256);

    // block 0 zero-inits out2 for k_gemv's atomics (kernel-boundary ordering)
    if (orig == 0) {
#pragma unroll
        for (int i = 0; i < 16; ++i) out2[i * 256 + t] = 0.f;
    }

    // Wave-private K-tile stage: wave (wr,wc) stages ONLY m = wc*256+kt*16+[0,16),
    // hi @ w*8192, lo @ w*8192+4096. Row r at r*256; byte x holds G[x ^ ((r&7)<<4)]
    // (same involution as the R6-verified shared path).
    char* const mybuf = smem + w * 8192;
    auto stagePriv = [&](int kt) {
        const char* srcH = (const char*)(g_S2H + (size_t)(b * 512 + wc * 256 + kt * 16) * 128);
        const char* srcL = (const char*)(g_S2L + (size_t)(b * 512 + wc * 256 + kt * 16) * 128);
#pragma unroll
        for (int j = 0; j < 4; ++j) {
            int r = j * 4 + q;   // local row this lane's q-group covers
            int so = r * 256 + ((fr * 16) ^ ((r & 7) << 4));
            gl_lds16(srcH + so, mybuf + j * 1024);
            gl_lds16(srcL + so, mybuf + 4096 + j * 1024);
        }
    };

    // ---- prologue: my K(0) in flight; overlaps Q setup (no barrier needed) ----
    stagePriv(0);

    // Q fragments: direct global f32 load + in-register hi/lo split (rows wr*16+fr)
    bf16x8 ah[4], al[4];
    {
        const float* qp = seq1 + (size_t)(b * 2048 + n0 + wr * 16 + fr) * 128;
#pragma unroll
        for (int ks = 0; ks < 4; ++ks) {
            float4 v0 = *(const float4*)(qp + ks * 32 + q * 8);
            float4 v1 = *(const float4*)(qp + ks * 32 + q * 8 + 4);
            float vs[8] = {v0.x, v0.y, v0.z, v0.w, v1.x, v1.y, v1.z, v1.w};
            unsigned short hh[8], ll[8];
#pragma unroll
            for (int j = 0; j < 8; ++j) { hh[j] = f2bf(vs[j]); ll[j] = f2bf(vs[j] - bf2f(hh[j])); }
            ah[ks] = *(bf16x8*)hh;
            al[ks] = *(bf16x8*)ll;
        }
    }

    f32x4 acc[8][2];
#pragma unroll
    for (int i = 0; i < 8; ++i) {
        acc[i][0] = (f32x4){0.f, 0.f, 0.f, 0.f};
        acc[i][1] = (f32x4){0.f, 0.f, 0.f, 0.f};
    }

    // ---- phase A: S = Q.K^T, split bf16 (3 MFMA), wave-private, ZERO barriers ----
    // acc[kt>>1][kt&1] lane (q,fr): S[n = wr*16 + q*4+r][m = wc*256 + kt*16 + fr]
    // per tile: wait my stage -> ds_read frags -> reads-done -> issue next stage
    //           -> MFMA (hides next stage's L2 latency; 16 waves/CU add TLP)
#pragma unroll
    for (int kt = 0; kt < 16; ++kt) {
        VMCNT0;            // my stage(kt) landed (wave-local)
        SCHED0;
        bf16x8 bh[4], bl[4];
        {
            const int sw = (fr & 7) << 4;
#pragma unroll
            for (int ks = 0; ks < 4; ++ks) {
                int off = (fr * 256 + ks * 64 + q * 16) ^ sw;
                bh[ks] = *(const bf16x8*)(mybuf + off);
                bl[ks] = *(const bf16x8*)(mybuf + 4096 + off);
            }
        }
        LGKMCNT0;          // my ds_reads done; buffer reusable
        SCHED0;
        if (kt < 15) stagePriv(kt + 1);   // issue next; flies under MFMAs below
        {
            f32x4 a = acc[kt >> 1][kt & 1];
            __builtin_amdgcn_s_setprio(1);
#pragma unroll
            for (int ks = 0; ks < 4; ++ks) {
                a = __builtin_amdgcn_mfma_f32_16x16x32_bf16(al[ks], bh[ks], a, 0, 0, 0);
                a = __builtin_amdgcn_mfma_f32_16x16x32_bf16(ah[ks], bl[ks], a, 0, 0, 0);
                a = __builtin_amdgcn_mfma_f32_16x16x32_bf16(ah[ks], bh[ks], a, 0, 0, 0);
            }
            __builtin_amdgcn_s_setprio(0);
            acc[kt >> 1][kt & 1] = a;
        }
    }
    __syncthreads();   // all waves done with private buffers; REDm/REDs overlay next

    // ---- phase B: masked softmax; m2 straight from global (L2-hot, 64-block reuse) ----
    // m = wc*256 + mt*32 + s*16 + fr
    {
        const int* m2p = m2 + b * 512 + wc * 256 + fr;
#pragma unroll
        for (int mt = 0; mt < 8; ++mt)
#pragma unroll
            for (int s = 0; s < 2; ++s) {
                bool keep = m2p[mt * 32 + s * 16] != 0;
#pragma unroll
                for (int r = 0; r < 4; ++r)
                    acc[mt][s][r] = keep ? acc[mt][s][r] : NEGC;
            }
    }
    float rmax[4];
#pragma unroll
    for (int r = 0; r < 4; ++r) rmax[r] = NEGC;
#pragma unroll
    for (int mt = 0; mt < 8; ++mt)
#pragma unroll
        for (int s = 0; s < 2; ++s)
#pragma unroll
            for (int r = 0; r < 4; ++r) rmax[r] = fmaxf(rmax[r], acc[mt][s][r]);
#pragma unroll
    for (int off = 1; off < 16; off <<= 1)
#pragma unroll
        for (int r = 0; r < 4; ++r) rmax[r] = fmaxf(rmax[r], __shfl_xor(rmax[r], off));
    if (fr == 0) {
#pragma unroll
        for (int r = 0; r < 4; ++r) REDm[wc * 32 + wr * 16 + q * 4 + r] = rmax[r];
    }
    __syncthreads();
    float RM[4];
#pragma unroll
    for (int r = 0; r < 4; ++r) {
        int rl = wr * 16 + q * 4 + r;
        RM[r] = fmaxf(REDm[rl], REDm[32 + rl]);
    }
    if (t < 32) {  // a1 logits -> static (k_gemv finalizes)
        float v = fmaxf(REDm[t], REDm[32 + t]);
        float m1v = (float)m1[b * 2048 + n0 + t];
        g_a1log[b * 2048 + n0 + t] = v + (1.0f - m1v) * NEGC;
    }
    float rs[4] = {0.f, 0.f, 0.f, 0.f};
#pragma unroll
    for (int mt = 0; mt < 8; ++mt)
#pragma unroll
        for (int s = 0; s < 2; ++s)
#pragma unroll
            for (int r = 0; r < 4; ++r) {
                float e = __expf(acc[mt][s][r] - RM[r]);
                acc[mt][s][r] = e;
                rs[r] += e;
            }
#pragma unroll
    for (int off = 1; off < 16; off <<= 1)
#pragma unroll
        for (int r = 0; r < 4; ++r) rs[r] += __shfl_xor(rs[r], off);
    if (fr == 0) {
#pragma unroll
        for (int r = 0; r < 4; ++r) REDs[wc * 32 + wr * 16 + q * 4 + r] = rs[r];
    }
    __syncthreads();
    float rinv[4];
#pragma unroll
    for (int r = 0; r < 4; ++r) {
        int rl = wr * 16 + q * 4 + r;
        rinv[r] = 1.0f / (REDs[rl] + REDs[32 + rl]);
    }
    __syncthreads();   // all waves done reading REDm/REDs before A2 overwrites region

    // write a2 (global f32, R12-proven interleaved scalar stores) + A2 bf16 to LDS @0
#pragma unroll
    for (int mt = 0; mt < 8; ++mt)
#pragma unroll
        for (int s = 0; s < 2; ++s) {
            int m = wc * 256 + mt * 32 + s * 16 + fr;
#pragma unroll
            for (int r = 0; r < 4; ++r) {
                int rl = wr * 16 + q * 4 + r;
                float v = acc[mt][s][r] * rinv[r];
                a2out[(size_t)(b * 2048 + n0 + rl) * 512 + m] = v;
                int off = (rl * 1024 + m * 2) ^ ((rl & 7) << 4);
                *(unsigned short*)(smem + off) = f2bf(v);
            }
        }
    __syncthreads();   // A2 ready

    // ---- phase C (R9-verified): out0 = a2.seq2; pa from A2 LDS, V-frags direct ----
    f32x4 oacc[4];
#pragma unroll
    for (int c = 0; c < 4; ++c) oacc[c] = (f32x4){0.f, 0.f, 0.f, 0.f};

    {
        const unsigned short* vf = g_VF + (size_t)b * 65536 + (size_t)wc * 32768 + lane * 8;
        const int arow = wr * 16 + fr;
        const int asw = (fr & 7) << 4;
        __builtin_amdgcn_s_setprio(1);
#pragma unroll
        for (int ms = 0; ms < 16; ++ms) {   // k = ms*32 + q*8
            bf16x8 bv[4];
#pragma unroll
            for (int c = 0; c < 4; ++c)
                bv[c] = *(const bf16x8*)(vf + ms * 2048 + c * 512);
            int aoff = (arow * 1024 + ms * 64 + q * 16) ^ asw;
            bf16x8 pa = *(const bf16x8*)(smem + aoff);
#pragma unroll
            for (int c = 0; c < 4; ++c)
                oacc[c] = __builtin_amdgcn_mfma_f32_16x16x32_bf16(pa, bv[c], oacc[c], 0, 0, 0);
        }
        __builtin_amdgcn_s_setprio(0);
    }

#pragma unroll
    for (int c = 0; c < 4; ++c)
#pragma unroll
        for (int r = 0; r < 4; ++r) {
            int rl = wr * 16 + q * 4 + r;
            int d = wc * 64 + c * 16 + fr;
            out0[(size_t)(b * 2048 + n0 + rl) * 128 + d] = oacc[c][r];
        }
}

// ---- fused tail: a1 softmax (from g_a1log) + a1 chunk store + GEMV chunk ----
__global__ __launch_bounds__(256) void k_gemv(const float* __restrict__ seq1,
                                              float* __restrict__ a1out,
                                              float* __restrict__ out2) {
    __shared__ float a1b[256];
    __shared__ float4 red[8][32];
    __shared__ float wred[4];
    const int bid = blockIdx.x, b = bid >> 3, ch = bid & 7, t = threadIdx.x;
    const int lane = t & 63, w = t >> 6;
    const int n0 = ch * 256;

    // per-batch softmax over 2048 logits (L2-hot; every block recomputes)
    const float4* Lp = (const float4*)(g_a1log + (size_t)b * 2048);
    float4 La = Lp[t * 2], Lb = Lp[t * 2 + 1];
    float l[8] = {La.x, La.y, La.z, La.w, Lb.x, Lb.y, Lb.z, Lb.w};

    float lmax = l[0];
#pragma unroll
    for (int j = 1; j < 8; ++j) lmax = fmaxf(lmax, l[j]);
#pragma unroll
    for (int off = 1; off < 64; off <<= 1) lmax = fmaxf(lmax, __shfl_xor(lmax, off));
    if (lane == 0) wred[w] = lmax;
    __syncthreads();
    float bmax = fmaxf(fmaxf(wred[0], wred[1]), fmaxf(wred[2], wred[3]));

    float e[8]; float s = 0.f;
#pragma unroll
    for (int j = 0; j < 8; ++j) { e[j] = __expf(l[j] - bmax); s += e[j]; }
#pragma unroll
    for (int off = 1; off < 64; off <<= 1) s += __shfl_xor(s, off);
    __syncthreads();
    if (lane == 0) wred[w] = s;
    __syncthreads();
    float inv = 1.0f / (wred[0] + wred[1] + wred[2] + wred[3]);

    // threads owning this chunk (t in [ch*32, ch*32+32)) stash weights + write a1
    if ((t >> 5) == ch) {
        float4 w0{e[0] * inv, e[1] * inv, e[2] * inv, e[3] * inv};
        float4 w1{e[4] * inv, e[5] * inv, e[6] * inv, e[7] * inv};
        int li = (t - ch * 32) * 8;
        *(float4*)(a1b + li) = w0;
        *(float4*)(a1b + li + 4) = w1;
        float4* ao = (float4*)(a1out + (size_t)b * 2048 + t * 8);
        ao[0] = w0;
        ao[1] = w1;
    }
    __syncthreads();

    // GEMV over this chunk's 256 rows
    const int d4 = t & 31, sl = t >> 5;
    float4 acc{0.f, 0.f, 0.f, 0.f};
    const float4* s1 = (const float4*)(seq1 + (size_t)(b * 2048 + n0 + sl * 32) * 128);
#pragma unroll 8
    for (int j = 0; j < 32; ++j) {
        float wv = a1b[sl * 32 + j];
        float4 v = s1[j * 32 + d4];
        acc.x += wv * v.x; acc.y += wv * v.y; acc.z += wv * v.z; acc.w += wv * v.w;
    }
    red[sl][d4] = acc;
    __syncthreads();
    if (t < 32) {
        float4 s0 = red[0][t];
#pragma unroll
        for (int c = 1; c < 8; ++c) {
            float4 v = red[c][t];
            s0.x += v.x; s0.y += v.y; s0.z += v.z; s0.w += v.w;
        }
        float* dst = out2 + b * 128 + t * 4;
        atomicAdd(dst + 0, s0.x);
        atomicAdd(dst + 1, s0.y);
        atomicAdd(dst + 2, s0.z);
        atomicAdd(dst + 3, s0.w);
    }
}

extern "C" void kernel_launch(void* const* d_in, const int* in_sizes, int n_in,
                              void* d_out, int out_size, void* d_ws, size_t ws_size,
                              hipStream_t stream) {
    const float* seq1 = (const float*)d_in[0];
    const float* seq2 = (const float*)d_in[1];
    const int*   m1   = (const int*)d_in[2];
    const int*   m2   = (const int*)d_in[3];
    (void)d_ws; (void)ws_size; (void)n_in; (void)in_sizes;

    float* out  = (float*)d_out;
    float* out0 = out;                 // [32,2048,128]
    float* a2o  = out + 8388608;       // [32,2048,512]
    float* o2   = out + 41943040;      // [32,128]
    float* a1o  = out + 41947136;      // [32,2048]

    k_prep<<<dim3(512), dim3(256), 0, stream>>>(seq2);
    bidir_main<<<dim3(2048), dim3(256), 0, stream>>>(seq1, m1, m2, out0, a2o, o2);
    k_gemv<<<dim3(256), dim3(256), 0, stream>>>(seq1, a1o, o2);
}

// Round 19
// 79.401 us; speedup vs baseline: 1.2717x; 1.2717x over previous
//
#include <hip/hip_runtime.h>
#include <stdint.h>

#define NEGC (-1.0e9f)

typedef __attribute__((ext_vector_type(8))) short bf16x8;
typedef __attribute__((ext_vector_type(4))) float f32x4;

// g_S2H/g_S2L: seq2 bf16 hi/lo row-major [b][m][d]   (phase-A staged source)
//   R16 lesson: the K-side lo correction is numerically load-bearing (dropping
//   it -> out0 absmax 0.113 > 0.101 threshold). 3-MFMA split stays.
//   R18 lesson: shared staging + barriers beats wave-private zero-barrier
//   (private: per-wave vmcnt(0) drains serialize, 2x traffic; 117us vs 62us).
// g_VF: V^T bf16 fragment-order chunks [b][wc 2][ms 16][c 4][lane 64][8]
//   lane l=(q*16+fr): V^T[d = wc*64+c*16+fr][m = ms*32+q*8 .. +8]   (R9-verified)
__device__ __align__(16) unsigned short g_S2H[32u * 512u * 128u];
__device__ __align__(16) unsigned short g_S2L[32u * 512u * 128u];
__device__ __align__(16) unsigned short g_VF[32u * 128u * 512u];
__device__ float g_a1log[32 * 2048];   // a1 logits (bidir_main -> k_gemv)

__device__ __forceinline__ unsigned short f2bf(float f) {
    union { float f; unsigned int u; } v; v.f = f;
    unsigned int r = v.u + 0x7fffu + ((v.u >> 16) & 1u);
    return (unsigned short)(r >> 16);
}
__device__ __forceinline__ float bf2f(unsigned short h) {
    union { float f; unsigned int u; } v; v.u = ((unsigned int)h) << 16;
    return v.f;
}

__device__ __forceinline__ void gl_lds16(const void* g, void* l) {
    __builtin_amdgcn_global_load_lds(
        (const __attribute__((address_space(1))) unsigned int*)g,
        (__attribute__((address_space(3))) unsigned int*)l, 16, 0, 0);
}

// ---- prep: seq2 -> row-major hi/lo split + fragment-order V^T. 512 blocks. ----
__global__ __launch_bounds__(256) void k_prep(const float* __restrict__ seq2) {
    __shared__ unsigned short Lh[32 * 136];
    const int b = blockIdx.x >> 4, c = blockIdx.x & 15, t = threadIdx.x;
    const int m0 = c * 32;

    // pass 1: rows [m0,+32) -> S2H/S2L row-major; hi also staged in LDS
    const float4* src = (const float4*)(seq2 + (size_t)(b * 512 + m0) * 128);
    ushort4* dh = (ushort4*)(g_S2H + (size_t)(b * 512 + m0) * 128);
    ushort4* dl = (ushort4*)(g_S2L + (size_t)(b * 512 + m0) * 128);
#pragma unroll
    for (int p = 0; p < 4; ++p) {
        int idx = p * 256 + t;
        int row = idx >> 5, c4 = idx & 31;
        float4 v = src[idx];
        float vs[4] = {v.x, v.y, v.z, v.w};
        unsigned short hh[4], ll[4];
#pragma unroll
        for (int i = 0; i < 4; ++i) { hh[i] = f2bf(vs[i]); ll[i] = f2bf(vs[i] - bf2f(hh[i])); }
        ushort4 uh{hh[0], hh[1], hh[2], hh[3]};
        ushort4 ul{ll[0], ll[1], ll[2], ll[3]};
        dh[idx] = uh;
        dl[idx] = ul;
#pragma unroll
        for (int i = 0; i < 4; ++i) Lh[row * 136 + c4 * 4 + i] = hh[i];
    }
    __syncthreads();

    // pass 2 (R9-verified): V-frags, this block's 32 m-cols = ms chunk (m0>>5)
    {
        const int l = t & 63, q = (t >> 4) & 3, fr = t & 15;
        const int ms = m0 >> 5;
#pragma unroll
        for (int pass = 0; pass < 2; ++pass) {
            int id = pass * 4 + (t >> 6);        // 0..7
            int wcd = id >> 2, cc = id & 3;
            int d = wcd * 64 + cc * 16 + fr;
            unsigned short pk[8];
#pragma unroll
            for (int j = 0; j < 8; ++j) pk[j] = Lh[(q * 8 + j) * 136 + d];
            size_t chunk = (size_t)b * 65536 + (size_t)wcd * 32768
                         + (size_t)ms * 2048 + cc * 512 + l * 8;
            *(bf16x8*)(g_VF + chunk) = *(bf16x8*)pk;
        }
    }
}

// ---- LDS layout (bytes): ONE 32K region, phase-overlaid ----
// phase A: K dbuf 2x16K {KH 8K|KL 8K}
// phase B: REDm @0 (256B), REDs @256 (256B)   (K region dead after phase A)
// phase C: A2 bf16 [32][512] @0 (32K)          (written after RED reads + barrier)
#define LDS_TOTAL 32768

__global__ __launch_bounds__(256, 4) void bidir_main(
    const float* __restrict__ seq1,
    const int* __restrict__ m1, const int* __restrict__ m2,
    float* __restrict__ out0, float* __restrict__ a2out,
    float* __restrict__ out2)
{
    __shared__ __align__(16) char smem[LDS_TOTAL];

    const int t = threadIdx.x, lane = t & 63, w = t >> 6;
    const int wr = w >> 1, wc = w & 1, q = lane >> 4, fr = lane & 15;
    const int orig = blockIdx.x;
    const int swzb = (orig & 7) * 256 + (orig >> 3);   // XCD-contiguous
    const int b = swzb >> 6, n0 = (swzb & 63) << 5;

    float* REDm = (float*)(smem);
    float* REDs = (float*)(smem + 256);

    // block 0 zero-inits out2 for k_gemv's atomics (kernel-boundary ordering)
    if (orig == 0) {
#pragma unroll
        for (int i = 0; i < 16; ++i) out2[i * 256 + t] = 0.f;
    }

    // K-tile stage (R6-verified): tile kt = m in [kt*16,+16) u [256+kt*16,+16), hi+lo.
    auto stageK = [&](int buf, int kt) {
        const unsigned short* sb = (w < 2) ? g_S2H : g_S2L;
        const int h = w & 1;
        const char* srcb = (const char*)(sb + (size_t)(b * 512 + h * 256 + kt * 16) * 128);
        char* dstb = smem + buf * 16384 + (w >> 1) * 8192 + h * 4096;
#pragma unroll
        for (int i = 0; i < 4; ++i) {
            int r = i * 4 + q;
            int so = r * 256 + ((fr * 16) ^ ((r & 7) << 4));
            gl_lds16(srcb + so, dstb + i * 1024);
        }
    };

    // ---- prologue: K(0) in flight; overlaps Q setup ----
    stageK(0, 0);

    // Q fragments: direct global f32 load + in-register hi/lo split (rows wr*16+fr)
    bf16x8 ah[4], al[4];
    {
        const float* qp = seq1 + (size_t)(b * 2048 + n0 + wr * 16 + fr) * 128;
#pragma unroll
        for (int ks = 0; ks < 4; ++ks) {
            float4 v0 = *(const float4*)(qp + ks * 32 + q * 8);
            float4 v1 = *(const float4*)(qp + ks * 32 + q * 8 + 4);
            float vs[8] = {v0.x, v0.y, v0.z, v0.w, v1.x, v1.y, v1.z, v1.w};
            unsigned short hh[8], ll[8];
#pragma unroll
            for (int j = 0; j < 8; ++j) { hh[j] = f2bf(vs[j]); ll[j] = f2bf(vs[j] - bf2f(hh[j])); }
            ah[ks] = *(bf16x8*)hh;
            al[ks] = *(bf16x8*)ll;
        }
    }

    f32x4 acc[8][2];
#pragma unroll
    for (int i = 0; i < 8; ++i) {
        acc[i][0] = (f32x4){0.f, 0.f, 0.f, 0.f};
        acc[i][1] = (f32x4){0.f, 0.f, 0.f, 0.f};
    }

    __syncthreads();   // K(0) ready

    // ---- phase A (R6-verified): S = Q.K^T, split bf16 (3 MFMA), dbuf 16 tiles ----
    // acc[kt>>1][kt&1] lane (q,fr): S[n = wr*16 + q*4+r][m = wc*256 + kt*16 + fr]
#pragma unroll
    for (int kt = 0; kt < 16; ++kt) {
        if (kt < 15) stageK((kt + 1) & 1, kt + 1);   // issue next BEFORE compute
        {
            const char* KH = smem + (kt & 1) * 16384;
            const char* KL = KH + 8192;
            const int rrow = wc * 16 + fr;
            const int sw = (fr & 7) << 4;
            f32x4 a = acc[kt >> 1][kt & 1];
            __builtin_amdgcn_s_setprio(1);
#pragma unroll
            for (int ks = 0; ks < 4; ++ks) {
                int off = (rrow * 256 + ks * 64 + q * 16) ^ sw;
                bf16x8 bh = *(const bf16x8*)(KH + off);
                bf16x8 bl = *(const bf16x8*)(KL + off);
                a = __builtin_amdgcn_mfma_f32_16x16x32_bf16(al[ks], bh, a, 0, 0, 0);
                a = __builtin_amdgcn_mfma_f32_16x16x32_bf16(ah[ks], bl, a, 0, 0, 0);
                a = __builtin_amdgcn_mfma_f32_16x16x32_bf16(ah[ks], bh, a, 0, 0, 0);
            }
            __builtin_amdgcn_s_setprio(0);
            acc[kt >> 1][kt & 1] = a;
        }
        __syncthreads();
    }
    // K region now dead; REDm/REDs overlay it.

    // ---- phase B: masked softmax; m2 straight from global (L2-hot, 64-block reuse) ----
    // m = wc*256 + mt*32 + s*16 + fr
    {
        const int* m2p = m2 + b * 512 + wc * 256 + fr;
#pragma unroll
        for (int mt = 0; mt < 8; ++mt)
#pragma unroll
            for (int s = 0; s < 2; ++s) {
                bool keep = m2p[mt * 32 + s * 16] != 0;
#pragma unroll
                for (int r = 0; r < 4; ++r)
                    acc[mt][s][r] = keep ? acc[mt][s][r] : NEGC;
            }
    }
    float rmax[4];
#pragma unroll
    for (int r = 0; r < 4; ++r) rmax[r] = NEGC;
#pragma unroll
    for (int mt = 0; mt < 8; ++mt)
#pragma unroll
        for (int s = 0; s < 2; ++s)
#pragma unroll
            for (int r = 0; r < 4; ++r) rmax[r] = fmaxf(rmax[r], acc[mt][s][r]);
#pragma unroll
    for (int off = 1; off < 16; off <<= 1)
#pragma unroll
        for (int r = 0; r < 4; ++r) rmax[r] = fmaxf(rmax[r], __shfl_xor(rmax[r], off));
    if (fr == 0) {
#pragma unroll
        for (int r = 0; r < 4; ++r) REDm[wc * 32 + wr * 16 + q * 4 + r] = rmax[r];
    }
    __syncthreads();
    float RM[4];
#pragma unroll
    for (int r = 0; r < 4; ++r) {
        int rl = wr * 16 + q * 4 + r;
        RM[r] = fmaxf(REDm[rl], REDm[32 + rl]);
    }
    if (t < 32) {  // a1 logits -> static (k_gemv finalizes)
        float v = fmaxf(REDm[t], REDm[32 + t]);
        float m1v = (float)m1[b * 2048 + n0 + t];
        g_a1log[b * 2048 + n0 + t] = v + (1.0f - m1v) * NEGC;
    }
    float rs[4] = {0.f, 0.f, 0.f, 0.f};
#pragma unroll
    for (int mt = 0; mt < 8; ++mt)
#pragma unroll
        for (int s = 0; s < 2; ++s)
#pragma unroll
            for (int r = 0; r < 4; ++r) {
                float e = __expf(acc[mt][s][r] - RM[r]);
                acc[mt][s][r] = e;
                rs[r] += e;
            }
#pragma unroll
    for (int off = 1; off < 16; off <<= 1)
#pragma unroll
        for (int r = 0; r < 4; ++r) rs[r] += __shfl_xor(rs[r], off);
    if (fr == 0) {
#pragma unroll
        for (int r = 0; r < 4; ++r) REDs[wc * 32 + wr * 16 + q * 4 + r] = rs[r];
    }
    __syncthreads();
    float rinv[4];
#pragma unroll
    for (int r = 0; r < 4; ++r) {
        int rl = wr * 16 + q * 4 + r;
        rinv[r] = 1.0f / (REDs[rl] + REDs[32 + rl]);
    }
    __syncthreads();   // all waves done reading REDm/REDs before A2 overwrites region

    // write a2 (global f32, R12-proven interleaved scalar stores) + A2 bf16 to LDS @0
#pragma unroll
    for (int mt = 0; mt < 8; ++mt)
#pragma unroll
        for (int s = 0; s < 2; ++s) {
            int m = wc * 256 + mt * 32 + s * 16 + fr;
#pragma unroll
            for (int r = 0; r < 4; ++r) {
                int rl = wr * 16 + q * 4 + r;
                float v = acc[mt][s][r] * rinv[r];
                a2out[(size_t)(b * 2048 + n0 + rl) * 512 + m] = v;
                int off = (rl * 1024 + m * 2) ^ ((rl & 7) << 4);
                *(unsigned short*)(smem + off) = f2bf(v);
            }
        }
    __syncthreads();   // A2 ready

    // ---- phase C (R9-verified): out0 = a2.seq2; pa from A2 LDS, V-frags direct ----
    f32x4 oacc[4];
#pragma unroll
    for (int c = 0; c < 4; ++c) oacc[c] = (f32x4){0.f, 0.f, 0.f, 0.f};

    {
        const unsigned short* vf = g_VF + (size_t)b * 65536 + (size_t)wc * 32768 + lane * 8;
        const int arow = wr * 16 + fr;
        const int asw = (fr & 7) << 4;
        __builtin_amdgcn_s_setprio(1);
#pragma unroll
        for (int ms = 0; ms < 16; ++ms) {   // k = ms*32 + q*8
            bf16x8 bv[4];
#pragma unroll
            for (int c = 0; c < 4; ++c)
                bv[c] = *(const bf16x8*)(vf + ms * 2048 + c * 512);
            int aoff = (arow * 1024 + ms * 64 + q * 16) ^ asw;
            bf16x8 pa = *(const bf16x8*)(smem + aoff);
#pragma unroll
            for (int c = 0; c < 4; ++c)
                oacc[c] = __builtin_amdgcn_mfma_f32_16x16x32_bf16(pa, bv[c], oacc[c], 0, 0, 0);
        }
        __builtin_amdgcn_s_setprio(0);
    }

#pragma unroll
    for (int c = 0; c < 4; ++c)
#pragma unroll
        for (int r = 0; r < 4; ++r) {
            int rl = wr * 16 + q * 4 + r;
            int d = wc * 64 + c * 16 + fr;
            out0[(size_t)(b * 2048 + n0 + rl) * 128 + d] = oacc[c][r];
        }
}

// ---- fused tail: a1 softmax (from g_a1log) + a1 chunk store + GEMV chunk ----
__global__ __launch_bounds__(256) void k_gemv(const float* __restrict__ seq1,
                                              float* __restrict__ a1out,
                                              float* __restrict__ out2) {
    __shared__ float a1b[256];
    __shared__ float4 red[8][32];
    __shared__ float wred[4];
    const int bid = blockIdx.x, b = bid >> 3, ch = bid & 7, t = threadIdx.x;
    const int lane = t & 63, w = t >> 6;
    const int n0 = ch * 256;

    // per-batch softmax over 2048 logits (L2-hot; every block recomputes)
    const float4* Lp = (const float4*)(g_a1log + (size_t)b * 2048);
    float4 La = Lp[t * 2], Lb = Lp[t * 2 + 1];
    float l[8] = {La.x, La.y, La.z, La.w, Lb.x, Lb.y, Lb.z, Lb.w};

    float lmax = l[0];
#pragma unroll
    for (int j = 1; j < 8; ++j) lmax = fmaxf(lmax, l[j]);
#pragma unroll
    for (int off = 1; off < 64; off <<= 1) lmax = fmaxf(lmax, __shfl_xor(lmax, off));
    if (lane == 0) wred[w] = lmax;
    __syncthreads();
    float bmax = fmaxf(fmaxf(wred[0], wred[1]), fmaxf(wred[2], wred[3]));

    float e[8]; float s = 0.f;
#pragma unroll
    for (int j = 0; j < 8; ++j) { e[j] = __expf(l[j] - bmax); s += e[j]; }
#pragma unroll
    for (int off = 1; off < 64; off <<= 1) s += __shfl_xor(s, off);
    __syncthreads();
    if (lane == 0) wred[w] = s;
    __syncthreads();
    float inv = 1.0f / (wred[0] + wred[1] + wred[2] + wred[3]);

    // threads owning this chunk (t in [ch*32, ch*32+32)) stash weights + write a1
    if ((t >> 5) == ch) {
        float4 w0{e[0] * inv, e[1] * inv, e[2] * inv, e[3] * inv};
        float4 w1{e[4] * inv, e[5] * inv, e[6] * inv, e[7] * inv};
        int li = (t - ch * 32) * 8;
        *(float4*)(a1b + li) = w0;
        *(float4*)(a1b + li + 4) = w1;
        float4* ao = (float4*)(a1out + (size_t)b * 2048 + t * 8);
        ao[0] = w0;
        ao[1] = w1;
    }
    __syncthreads();

    // GEMV over this chunk's 256 rows
    const int d4 = t & 31, sl = t >> 5;
    float4 acc{0.f, 0.f, 0.f, 0.f};
    const float4* s1 = (const float4*)(seq1 + (size_t)(b * 2048 + n0 + sl * 32) * 128);
#pragma unroll 8
    for (int j = 0; j < 32; ++j) {
        float wv = a1b[sl * 32 + j];
        float4 v = s1[j * 32 + d4];
        acc.x += wv * v.x; acc.y += wv * v.y; acc.z += wv * v.z; acc.w += wv * v.w;
    }
    red[sl][d4] = acc;
    __syncthreads();
    if (t < 32) {
        float4 s0 = red[0][t];
#pragma unroll
        for (int c = 1; c < 8; ++c) {
            float4 v = red[c][t];
            s0.x += v.x; s0.y += v.y; s0.z += v.z; s0.w += v.w;
        }
        float* dst = out2 + b * 128 + t * 4;
        atomicAdd(dst + 0, s0.x);
        atomicAdd(dst + 1, s0.y);
        atomicAdd(dst + 2, s0.z);
        atomicAdd(dst + 3, s0.w);
    }
}

extern "C" void kernel_launch(void* const* d_in, const int* in_sizes, int n_in,
                              void* d_out, int out_size, void* d_ws, size_t ws_size,
                              hipStream_t stream) {
    const float* seq1 = (const float*)d_in[0];
    const float* seq2 = (const float*)d_in[1];
    const int*   m1   = (const int*)d_in[2];
    const int*   m2   = (const int*)d_in[3];
    (void)d_ws; (void)ws_size; (void)n_in; (void)in_sizes;

    float* out  = (float*)d_out;
    float* out0 = out;                 // [32,2048,128]
    float* a2o  = out + 8388608;       // [32,2048,512]
    float* o2   = out + 41943040;      // [32,128]
    float* a1o  = out + 41947136;      // [32,2048]

    k_prep<<<dim3(512), dim3(256), 0, stream>>>(seq2);
    bidir_main<<<dim3(2048), dim3(256), 0, stream>>>(seq1, m1, m2, out0, a2o, o2);
    k_gemv<<<dim3(256), dim3(256), 0, stream>>>(seq1, a1o, o2);
}